// Round 4
// baseline (397.478 us; speedup 1.0000x reference)
//
#include <hip/hip_runtime.h>
#include <stdint.h>

// Problem constants (n=6, d=1024, T=4096)
#define T_STEPS 4096
#define DDIM    1024
// covariance pipeline chunking
#define CHC     64    // chunks
#define CLC     64    // steps per chunk
// means pipeline chunking (latency-bound -> shorter serial chains, more blocks)
#define CHM     128
#define CLM     32
#define MEAN_ELEMS ((size_t)T_STEPS * 6 * DDIM)   // 25,165,824

__device__ __forceinline__ float bf2f(uint16_t h){
    return __uint_as_float(((uint32_t)h) << 16);
}
__device__ __forceinline__ uint16_t f2bf(float f){   // round-to-nearest-even
    uint32_t u = __float_as_uint(f);
    uint32_t r = 0x7FFFu + ((u >> 16) & 1u);
    return (uint16_t)((u + r) >> 16);
}
// dtype-flag-aware scalar load (flag: 1 = inputs are float32, 0 = bf16)
__device__ __forceinline__ float ld(const void* p, size_t idx, bool f32){
    return f32 ? ((const float*)p)[idx] : bf2f(((const uint16_t*)p)[idx]);
}

// ---------------------------------------------------------------------------
// K0: input dtype detection (low 16 bits of f32 words are mantissa garbage).
// ---------------------------------------------------------------------------
__global__ void k0_detect(const void* __restrict__ imean, uint32_t* __restrict__ flag){
    const uint32_t* w = (const uint32_t*)imean;
    int good = 0;
    for (int i = threadIdx.x; i < 3072; i += 64){
        float v = bf2f((uint16_t)(w[i] & 0xFFFFu));
        float a = fabsf(v);
        if (a > 1e-6f && a < 1e4f) good++;
    }
    #pragma unroll
    for (int ofs = 32; ofs >= 1; ofs >>= 1) good += __shfl_xor(good, ofs, 64);
    if (threadIdx.x == 0) flag[0] = (good < 2000) ? 1u : 0u;
}

// ---------------------------------------------------------------------------
// K1: per-chunk composition M' = A M A^T + N (Gram recursion), 64-step chunks.
// Dual P accumulators: f64 full-chunk product (covs) + f32 half-chunk
// products Pf[2c],Pf[2c+1] for the means pipeline (32-step chunks).
// ---------------------------------------------------------------------------
__global__ void k1_chunk_compose(const void* __restrict__ trans,
                                 const void* __restrict__ ncov,
                                 double* __restrict__ Pd, double* __restrict__ Qd,
                                 float* __restrict__ Af, float* __restrict__ Pf,
                                 const uint32_t* __restrict__ flag){
    __shared__ double A_ds[36], n_ds[36], P_ds[36], Q_ds[36], T_ds[36];
    __shared__ float Afs[36], P2_ds[36];
    const bool f32 = flag[0] != 0;
    const int c = blockIdx.x;
    const int e = threadIdx.x;
    const int i = e / 6, j = e % 6;
    float aCur = 0.f, nCur = 0.f;
    if (e < 36){
        P_ds[e] = (i == j) ? 1.0 : 0.0; Q_ds[e] = 0.0;
        aCur = ld(trans, (size_t)c*CLC*36 + e, f32);
        nCur = ld(ncov,  (size_t)c*CLC*36 + e, f32);
    }
    __syncthreads();
    for (int s = 0; s < CLC; ++s){
        const int k = c * CLC + s;
        if (e < 36){
            Af[k*36 + e] = aCur;
            A_ds[e] = (double)aCur;
            Afs[e]  = aCur;
            n_ds[e] = (double)nCur;
        }
        __syncthreads();
        // next step's independent loads (hidden behind matmuls)
        if (e < 36 && s + 1 < CLC){
            aCur = ld(trans, (size_t)(k+1)*36 + e, f32);
            nCur = ld(ncov,  (size_t)(k+1)*36 + e, f32);
        }
        double newP = 0.0, Tij = 0.0;
        float t2 = 0.f;
        if (e < 36){
            #pragma unroll
            for (int m = 0; m < 6; ++m){
                newP += A_ds[i*6+m] * P_ds[m*6+j];
                Tij  += A_ds[i*6+m] * Q_ds[m*6+j];
            }
            if (s >= CLC/2){
                #pragma unroll
                for (int m = 0; m < 6; ++m) t2 += Afs[i*6+m] * P2_ds[m*6+j];
            }
        }
        __syncthreads();
        if (e < 36){
            P_ds[e] = newP; T_ds[e] = Tij;
            if (s == CLC/2 - 1){
                Pf[(2*c)*36 + e] = (float)newP;     // product of first 32 A's
                P2_ds[e] = (i == j) ? 1.f : 0.f;    // restart for second half
            } else if (s >= CLC/2){
                P2_ds[e] = t2;
            }
        }
        __syncthreads();
        double qn = 0.0;
        if (e < 36){
            #pragma unroll
            for (int m = 0; m < 6; ++m){
                qn += T_ds[i*6+m] * A_ds[j*6+m];   // (A Q) A^T
                qn += n_ds[i*6+m] * n_ds[j*6+m];   // + n n^T
            }
        }
        __syncthreads();
        if (e < 36) Q_ds[e] = qn;
        __syncthreads();
    }
    if (e < 36){
        Pd[c*36+e] = P_ds[e];
        Qd[c*36+e] = Q_ds[e];
        Pf[(2*c+1)*36+e] = P2_ds[e];               // product of last 32 A's
    }
}

// ---------------------------------------------------------------------------
// K2: boundary scan, ALL (P,Q) preloaded to LDS (64*72*8 = 36.9 KB).
// ---------------------------------------------------------------------------
__global__ void k2_boundary_scan(const void* __restrict__ icov,
                                 const double* __restrict__ Pd,
                                 const double* __restrict__ Qd,
                                 double* __restrict__ Mb,
                                 const uint32_t* __restrict__ flag){
    __shared__ double Ps[CHC][36], Qs[CHC][36];
    __shared__ double M_ds[36], T_ds[36], l_ds[36];
    const bool f32 = flag[0] != 0;
    const int e = threadIdx.x;
    const int i = e / 6, j = e % 6;
    for (int idx = e; idx < CHC*36; idx += 64){
        Ps[idx/36][idx%36] = Pd[idx];
        Qs[idx/36][idx%36] = Qd[idx];
    }
    if (e < 36) l_ds[e] = (double)ld(icov, e, f32);
    __syncthreads();
    if (e < 36){
        double m = 0.0;
        #pragma unroll
        for (int mm = 0; mm < 6; ++mm) m += l_ds[i*6+mm] * l_ds[j*6+mm];
        M_ds[e] = m; Mb[e] = m;
    }
    __syncthreads();
    for (int c = 0; c < CHC - 1; ++c){
        double t = 0.0;
        if (e < 36){
            #pragma unroll
            for (int m = 0; m < 6; ++m) t += Ps[c][i*6+m] * M_ds[m*6+j];
        }
        __syncthreads();
        if (e < 36) T_ds[e] = t;
        __syncthreads();
        double mn = 0.0;
        if (e < 36){
            #pragma unroll
            for (int m = 0; m < 6; ++m) mn += T_ds[i*6+m] * Ps[c][j*6+m];
            mn += Qs[c][e];
        }
        __syncthreads();
        if (e < 36){ M_ds[e] = mn; Mb[(c+1)*36 + e] = mn; }
        __syncthreads();
    }
}

// ---------------------------------------------------------------------------
// K34: fused M-expansion (to LDS) + 64 per-thread Householder QRs per block.
// Phase A: block serially advances M through its 64 steps, storing each to LDS.
// Phase B: thread s does the 12x6 QR for step c*64+s (LAPACK dlarfg signs).
// Sign algebra: qr(diag(sigma,I)X).R == sigma*qr(X).R bitwise -> masks/XOR scan.
// ---------------------------------------------------------------------------
__global__ void __launch_bounds__(64)
k34_qr(const void* __restrict__ trans,
       const void* __restrict__ ncov,
       const void* __restrict__ icov,
       const double* __restrict__ Mb,
       void* __restrict__ d_out,
       uint32_t* __restrict__ masks,
       const uint32_t* __restrict__ flag){
    __shared__ double Mlds[CLC][36];
    __shared__ double A_ds[36], n_ds[36], M_ds[36], T_ds[36];
    const bool f32 = flag[0] != 0;
    const int c = blockIdx.x;
    const int e = threadIdx.x;
    const int i = e / 6, j = e % 6;

    // ---- Phase A: expand M across the chunk into LDS ----
    float aCur = 0.f, nCur = 0.f;
    if (e < 36){
        M_ds[e] = Mb[c*36 + e];
        aCur = ld(trans, (size_t)c*CLC*36 + e, f32);
        nCur = ld(ncov,  (size_t)c*CLC*36 + e, f32);
    }
    __syncthreads();
    for (int s = 0; s < CLC; ++s){
        const int k = c * CLC + s;
        if (e < 36) Mlds[s][e] = M_ds[e];
        if (s == CLC - 1) break;             // uniform branch
        if (e < 36){
            A_ds[e] = (double)aCur;
            n_ds[e] = (double)nCur;
        }
        __syncthreads();
        if (e < 36 && s + 1 < CLC - 1){
            aCur = ld(trans, (size_t)(k+1)*36 + e, f32);
            nCur = ld(ncov,  (size_t)(k+1)*36 + e, f32);
        }
        double t = 0.0;
        if (e < 36){
            #pragma unroll
            for (int m = 0; m < 6; ++m) t += A_ds[i*6+m] * M_ds[m*6+j];
        }
        __syncthreads();
        if (e < 36) T_ds[e] = t;
        __syncthreads();
        double mn = 0.0;
        if (e < 36){
            #pragma unroll
            for (int m = 0; m < 6; ++m){
                mn += T_ds[i*6+m] * A_ds[j*6+m];
                mn += n_ds[i*6+m] * n_ds[j*6+m];
            }
        }
        __syncthreads();
        if (e < 36) M_ds[e] = mn;
        __syncthreads();
    }
    __syncthreads();

    // ---- Phase B: per-thread QR for step k = c*CLC + e ----
    const int k = c * CLC + e;
    double X[12][6];

    if (k == 0){
        double l0[6][6], A0[6][6];
        #pragma unroll
        for (int a = 0; a < 36; ++a){
            l0[a/6][a%6] = (double)ld(icov, a, f32);
            A0[a/6][a%6] = (double)ld(trans, a, f32);
        }
        #pragma unroll
        for (int i2 = 0; i2 < 6; ++i2)
            #pragma unroll
            for (int j2 = 0; j2 < 6; ++j2){
                double s = 0.0;
                #pragma unroll
                for (int m = 0; m < 6; ++m) s += A0[i2][m] * l0[m][j2];
                X[j2][i2] = s;               // top block = (A l)^T
            }
    } else {
        double M[6][6];
        #pragma unroll
        for (int a = 0; a < 36; ++a) M[a/6][a%6] = Mlds[e][a];
        // Cholesky in place (lower triangle of M becomes C)
        #pragma unroll
        for (int j2 = 0; j2 < 6; ++j2){
            double d = M[j2][j2];
            #pragma unroll
            for (int m = 0; m < 6; ++m) if (m < j2) d -= M[j2][m]*M[j2][m];
            d = (d > 1e-300) ? d : 1e-300;
            double cjj = sqrt(d);
            M[j2][j2] = cjj;
            double inv = 1.0 / cjj;
            #pragma unroll
            for (int i2 = 0; i2 < 6; ++i2){
                if (i2 > j2){
                    double s = M[i2][j2];
                    #pragma unroll
                    for (int m = 0; m < 6; ++m) if (m < j2) s -= M[i2][m]*M[j2][m];
                    M[i2][j2] = s * inv;
                }
            }
        }
        #pragma unroll
        for (int i2 = 0; i2 < 6; ++i2){
            double Arow[6];
            #pragma unroll
            for (int m = 0; m < 6; ++m) Arow[m] = (double)ld(trans, (size_t)k*36 + i2*6 + m, f32);
            #pragma unroll
            for (int j2 = 0; j2 < 6; ++j2){
                double s = 0.0;
                #pragma unroll
                for (int m = 0; m < 6; ++m) if (m >= j2) s += Arow[m] * M[m][j2];
                X[j2][i2] = s;               // top block = (A C)^T
            }
        }
    }
    // bottom block = n^T
    #pragma unroll
    for (int r = 0; r < 6; ++r)
        #pragma unroll
        for (int c2 = 0; c2 < 6; ++c2)
            X[6+r][c2] = (double)ld(ncov, (size_t)k*36 + c2*6 + r, f32);

    // In-place Householder QR, LAPACK sign convention: beta = -sign(alpha)*norm
    #pragma unroll
    for (int kk = 0; kk < 6; ++kk){
        double alpha = X[kk][kk];
        double xn2 = 0.0;
        #pragma unroll
        for (int i2 = 0; i2 < 12; ++i2) if (i2 > kk) xn2 += X[i2][kk]*X[i2][kk];
        if (xn2 != 0.0){
            double nrm  = sqrt(alpha*alpha + xn2);
            double beta = (alpha >= 0.0) ? -nrm : nrm;
            double tau  = (beta - alpha) / beta;
            double sc   = 1.0 / (alpha - beta);
            #pragma unroll
            for (int i2 = 0; i2 < 12; ++i2) if (i2 > kk) X[i2][kk] *= sc;  // v in place
            X[kk][kk] = beta;
            #pragma unroll
            for (int j2 = 0; j2 < 6; ++j2){
                if (j2 > kk){
                    double w = X[kk][j2];
                    #pragma unroll
                    for (int i2 = 0; i2 < 12; ++i2) if (i2 > kk) w += X[i2][kk]*X[i2][j2];
                    double wt = tau * w;
                    X[kk][j2] -= wt;
                    #pragma unroll
                    for (int i2 = 0; i2 < 12; ++i2) if (i2 > kk) X[i2][j2] -= X[i2][kk]*wt;
                }
            }
        } // xn2==0: H=I, R[kk][kk]=alpha (LAPACK), nothing to do
    }

    uint32_t mask = 0;
    #pragma unroll
    for (int j2 = 0; j2 < 6; ++j2) if (X[j2][j2] < 0.0) mask |= (1u << j2);
    masks[k] = mask;

    if (f32){
        float* o = (float*)d_out + MEAN_ELEMS + (size_t)k*36;
        #pragma unroll
        for (int i2 = 0; i2 < 6; ++i2)
            #pragma unroll
            for (int j2 = 0; j2 < 6; ++j2)
                o[i2*6 + j2] = (j2 <= i2) ? (float)X[j2][i2] : 0.0f;
    } else {
        uint16_t* o = (uint16_t*)d_out + MEAN_ELEMS + (size_t)k*36;
        #pragma unroll
        for (int i2 = 0; i2 < 6; ++i2)
            #pragma unroll
            for (int j2 = 0; j2 < 6; ++j2)
                o[i2*6 + j2] = f2bf((j2 <= i2) ? (float)X[j2][i2] : 0.0f);
    }
}

// K5: XOR prefix-scan of sign masks. amask[k] = masks[0]^...^masks[k-1].
__global__ void k5_scan(const uint32_t* __restrict__ masks, uint32_t* __restrict__ amask){
    const int lane = threadIdx.x;
    const int base = lane * 64;
    uint32_t tot = 0;
    #pragma unroll
    for (int i2 = 0; i2 < 64; ++i2) tot ^= masks[base + i2];
    uint32_t incl = tot;
    #pragma unroll
    for (int ofs = 1; ofs < 64; ofs <<= 1){
        uint32_t up = (uint32_t)__shfl_up((int)incl, ofs, 64);
        if (lane >= ofs) incl ^= up;
    }
    uint32_t run = incl ^ tot;               // exclusive prefix of lane segment
    #pragma unroll
    for (int i2 = 0; i2 < 64; ++i2){
        amask[base + i2] = run;
        run ^= masks[base + i2];
    }
}

// K6: apply column sign flips to covs[k], k>=1. One thread per element.
__global__ void __launch_bounds__(256)
k6_apply(void* __restrict__ d_out, const uint32_t* __restrict__ amask,
         const uint32_t* __restrict__ flag){
    const int idx = blockIdx.x * 256 + threadIdx.x;   // 0 .. 4096*36-1
    const int k = idx / 36;
    const int e = idx % 36;
    if (k == 0) return;
    if (!((amask[k] >> (e % 6)) & 1u)) return;
    if (flag[0]) ((uint32_t*)d_out)[MEAN_ELEMS + (size_t)k*36 + e] ^= 0x80000000u;
    else         ((uint16_t*)d_out)[MEAN_ELEMS + (size_t)k*36 + e] ^= 0x8000u;
}

// ---------------------------------------------------------------------------
// Means pipeline: m_t = A_t m_{t-1} + b_t. 128 chunks x 32 steps, 1 col/thread
// (512 blocks -> 8 waves/CU), ping-pong register prefetch of A and nmean.
// ---------------------------------------------------------------------------
template<bool F32>
__device__ __forceinline__ float ldn(const void* nmean, int k, int i, int col){
    if (F32) return ((const float*)nmean)[(size_t)k*6144 + i*DDIM + col];
    return bf2f(((const uint16_t*)nmean)[(size_t)k*6144 + i*DDIM + col]);
}

template<bool F32>
__device__ __forceinline__ void km1_body(const void* nmean, const float* Af,
                                         float* r_ws, int c, int col){
    float r[6];
    #pragma unroll
    for (int i = 0; i < 6; ++i) r[i] = 0.f;
    float aA[36], nA[6], aB[36], nB[6];
    {
        const float* A = Af + (size_t)c*CLM*36;
        #pragma unroll
        for (int t = 0; t < 36; ++t) aA[t] = A[t];
        #pragma unroll
        for (int i = 0; i < 6; ++i) nA[i] = ldn<F32>(nmean, c*CLM, i, col);
    }
    for (int s = 0; s < CLM; s += 2){
        const int k = c*CLM + s;
        {   // prefetch step s+1 into B
            const float* A = Af + (size_t)(k+1)*36;
            #pragma unroll
            for (int t = 0; t < 36; ++t) aB[t] = A[t];
            #pragma unroll
            for (int i = 0; i < 6; ++i) nB[i] = ldn<F32>(nmean, k+1, i, col);
        }
        float t0[6];
        #pragma unroll
        for (int i = 0; i < 6; ++i){
            float s0 = nA[i];
            #pragma unroll
            for (int m = 0; m < 6; ++m) s0 += aA[i*6+m]*r[m];
            t0[i] = s0;
        }
        if (s + 2 < CLM){   // prefetch step s+2 into A
            const float* A = Af + (size_t)(k+2)*36;
            #pragma unroll
            for (int t = 0; t < 36; ++t) aA[t] = A[t];
            #pragma unroll
            for (int i = 0; i < 6; ++i) nA[i] = ldn<F32>(nmean, k+2, i, col);
        }
        #pragma unroll
        for (int i = 0; i < 6; ++i){
            float s0 = nB[i];
            #pragma unroll
            for (int m = 0; m < 6; ++m) s0 += aB[i*6+m]*t0[m];
            r[i] = s0;
        }
    }
    float* out = r_ws + (size_t)c*6144;
    #pragma unroll
    for (int i = 0; i < 6; ++i) out[i*DDIM + col] = r[i];
}

__global__ void __launch_bounds__(256)
km1_chunk_r(const void* __restrict__ nmean, const float* __restrict__ Af,
            float* __restrict__ r_ws, const uint32_t* __restrict__ flag){
    const int c   = blockIdx.x >> 2;
    const int col = (blockIdx.x & 3)*256 + threadIdx.x;
    if (flag[0]) km1_body<true>(nmean, Af, r_ws, c, col);
    else         km1_body<false>(nmean, Af, r_ws, c, col);
}

// KM2: chunk-boundary scan with 1-chunk-ahead register prefetch of r and P.
__global__ void __launch_bounds__(128)
km2_scan(const void* __restrict__ imean,
         const float* __restrict__ Pf,
         const float* __restrict__ r_ws,
         float* __restrict__ mb_ws,
         const uint32_t* __restrict__ flag){
    const bool f32 = flag[0] != 0;
    const int col = blockIdx.x*128 + threadIdx.x;   // 8 blocks x 128 = 1024 cols
    float m[6];
    #pragma unroll
    for (int i = 0; i < 6; ++i) m[i] = ld(imean, (size_t)i*DDIM + col, f32);
    float rA[6], pA[36];
    #pragma unroll
    for (int i = 0; i < 6; ++i) rA[i] = r_ws[i*DDIM + col];
    #pragma unroll
    for (int t = 0; t < 36; ++t) pA[t] = Pf[t];
    for (int c = 0; c < CHM; ++c){
        float rB[6], pB[36];
        if (c + 1 < CHM){                    // independent loads: issue early
            const float* rn = r_ws + (size_t)(c+1)*6144;
            #pragma unroll
            for (int i = 0; i < 6; ++i) rB[i] = rn[i*DDIM + col];
            const float* pn = Pf + (size_t)(c+1)*36;
            #pragma unroll
            for (int t = 0; t < 36; ++t) pB[t] = pn[t];
        }
        float* mb = mb_ws + (size_t)c*6144;
        #pragma unroll
        for (int i = 0; i < 6; ++i) mb[i*DDIM + col] = m[i];
        float nm[6];
        #pragma unroll
        for (int i = 0; i < 6; ++i){
            float s0 = rA[i];
            #pragma unroll
            for (int mm = 0; mm < 6; ++mm) s0 += pA[i*6+mm]*m[mm];
            nm[i] = s0;
        }
        #pragma unroll
        for (int i = 0; i < 6; ++i) m[i] = nm[i];
        if (c + 1 < CHM){
            #pragma unroll
            for (int i = 0; i < 6; ++i) rA[i] = rB[i];
            #pragma unroll
            for (int t = 0; t < 36; ++t) pA[t] = pB[t];
        }
    }
}

// KM3: replay within chunk from exact boundary, write means (dtype-aware).
template<bool F32>
__device__ __forceinline__ void km3_body(const void* nmean, const float* Af,
                                         const float* mb_ws, void* means_out,
                                         int c, int col){
    float r[6];
    const float* mb = mb_ws + (size_t)c*6144;
    #pragma unroll
    for (int i = 0; i < 6; ++i) r[i] = mb[i*DDIM + col];
    float aA[36], nA[6], aB[36], nB[6];
    {
        const float* A = Af + (size_t)c*CLM*36;
        #pragma unroll
        for (int t = 0; t < 36; ++t) aA[t] = A[t];
        #pragma unroll
        for (int i = 0; i < 6; ++i) nA[i] = ldn<F32>(nmean, c*CLM, i, col);
    }
    for (int s = 0; s < CLM; s += 2){
        const int k = c*CLM + s;
        {
            const float* A = Af + (size_t)(k+1)*36;
            #pragma unroll
            for (int t = 0; t < 36; ++t) aB[t] = A[t];
            #pragma unroll
            for (int i = 0; i < 6; ++i) nB[i] = ldn<F32>(nmean, k+1, i, col);
        }
        float t0[6];
        #pragma unroll
        for (int i = 0; i < 6; ++i){
            float s0 = nA[i];
            #pragma unroll
            for (int m = 0; m < 6; ++m) s0 += aA[i*6+m]*r[m];
            t0[i] = s0;
            if (F32) ((float*)means_out)[(size_t)k*6144 + i*DDIM + col] = s0;
            else     ((uint16_t*)means_out)[(size_t)k*6144 + i*DDIM + col] = f2bf(s0);
        }
        if (s + 2 < CLM){
            const float* A = Af + (size_t)(k+2)*36;
            #pragma unroll
            for (int t = 0; t < 36; ++t) aA[t] = A[t];
            #pragma unroll
            for (int i = 0; i < 6; ++i) nA[i] = ldn<F32>(nmean, k+2, i, col);
        }
        #pragma unroll
        for (int i = 0; i < 6; ++i){
            float s0 = nB[i];
            #pragma unroll
            for (int m = 0; m < 6; ++m) s0 += aB[i*6+m]*t0[m];
            r[i] = s0;
            if (F32) ((float*)means_out)[(size_t)(k+1)*6144 + i*DDIM + col] = s0;
            else     ((uint16_t*)means_out)[(size_t)(k+1)*6144 + i*DDIM + col] = f2bf(s0);
        }
    }
}

__global__ void __launch_bounds__(256)
km3_final(const void* __restrict__ nmean, const float* __restrict__ Af,
          const float* __restrict__ mb_ws, void* __restrict__ means_out,
          const uint32_t* __restrict__ flag){
    const int c   = blockIdx.x >> 2;
    const int col = (blockIdx.x & 3)*256 + threadIdx.x;
    if (flag[0]) km3_body<true>(nmean, Af, mb_ws, means_out, c, col);
    else         km3_body<false>(nmean, Af, mb_ws, means_out, c, col);
}

// ---------------------------------------------------------------------------
extern "C" void kernel_launch(void* const* d_in, const int* in_sizes, int n_in,
                              void* d_out, int out_size, void* d_ws, size_t ws_size,
                              hipStream_t stream){
    (void)in_sizes; (void)n_in; (void)out_size; (void)ws_size;
    const void* imean = d_in[0];  // [6,1024]
    const void* icov  = d_in[1];  // [6,6]
    const void* trans = d_in[2];  // [T,6,6]
    const void* nmean = d_in[3];  // [T,6,1024]
    const void* ncov  = d_in[4];  // [T,6,6]

    // workspace layout (8-byte types first; ~7.2 MB total)
    char* w = (char*)d_ws;
    double* Pd   = (double*)w; w += (size_t)CHC*36*8;
    double* Qd   = (double*)w; w += (size_t)CHC*36*8;
    double* Mb   = (double*)w; w += (size_t)CHC*36*8;
    float*  Af   = (float*)w;  w += (size_t)T_STEPS*36*4;
    float*  Pf   = (float*)w;  w += (size_t)CHM*36*4;
    uint32_t* masks = (uint32_t*)w; w += (size_t)T_STEPS*4;
    uint32_t* amask = (uint32_t*)w; w += (size_t)T_STEPS*4;
    uint32_t* flag  = (uint32_t*)w; w += 8;
    float* r_ws  = (float*)w;  w += (size_t)CHM*6*DDIM*4;
    float* mb_ws = (float*)w;  w += (size_t)CHM*6*DDIM*4;

    k0_detect<<<1, 64, 0, stream>>>(imean, flag);
    k1_chunk_compose<<<CHC, 64, 0, stream>>>(trans, ncov, Pd, Qd, Af, Pf, flag);
    km1_chunk_r<<<4*CHM, 256, 0, stream>>>(nmean, Af, r_ws, flag);
    km2_scan<<<8, 128, 0, stream>>>(imean, Pf, r_ws, mb_ws, flag);
    km3_final<<<4*CHM, 256, 0, stream>>>(nmean, Af, mb_ws, d_out, flag);
    k2_boundary_scan<<<1, 64, 0, stream>>>(icov, Pd, Qd, Mb, flag);
    k34_qr<<<CHC, 64, 0, stream>>>(trans, ncov, icov, Mb, d_out, masks, flag);
    k5_scan<<<1, 64, 0, stream>>>(masks, amask);
    k6_apply<<<(T_STEPS*36)/256, 256, 0, stream>>>(d_out, amask, flag);
}